// Round 1
// baseline (3387.737 us; speedup 1.0000x reference)
//
#include <hip/hip_runtime.h>

#define D 64
#define F 128

// ---------------- degree ----------------
__global__ __launch_bounds__(256) void k_deg(const int* __restrict__ src,
                                             float* __restrict__ deg, int E) {
  int i = blockIdx.x * 256 + threadIdx.x;
  if (i < E) atomicAdd(&deg[src[i]], 1.0f);
}

__global__ __launch_bounds__(256) void k_invdeg(float* __restrict__ deg, int N) {
  int i = blockIdx.x * 256 + threadIdx.x;
  if (i < N) deg[i] = 1.0f / fmaxf(deg[i], 1.0f);
}

// ---------------- input projection: x = nf@w + b (+picked bias), h = relu(x)
__global__ __launch_bounds__(256) void k_input(
    const float* __restrict__ nf, const float* __restrict__ w,
    const float* __restrict__ bias, const float* __restrict__ bpick,
    const int* __restrict__ picked, float* __restrict__ x,
    float* __restrict__ h, int N) {
  __shared__ float aT[64 * 68];  // aT[k*68+row] = nf[r0+row][kc+k]
  __shared__ float bs[64 * 64];  // bs[k*64+col] = w[kc+k][col]
  const int tid = threadIdx.x;
  const int r0 = blockIdx.x * 64;
  const int tcol = tid & 15, trow = tid >> 4;
  float acc[4][4];
#pragma unroll
  for (int r = 0; r < 4; ++r)
#pragma unroll
    for (int j = 0; j < 4; ++j) acc[r][j] = bias[tcol * 4 + j];

  for (int kc = 0; kc < F; kc += 64) {
    if (kc) __syncthreads();
    for (int i = tid; i < 64 * 64; i += 256) {
      int row = i >> 6, k = i & 63;
      int gr = r0 + row;
      aT[k * 68 + row] = (gr < N) ? nf[(size_t)gr * F + kc + k] : 0.0f;
    }
    for (int i = tid; i < 64 * 64; i += 256) bs[i] = w[kc * 64 + i];
    __syncthreads();
#pragma unroll 8
    for (int k = 0; k < 64; ++k) {
      float4 av = *(const float4*)&aT[k * 68 + trow * 4];
      float4 bv = *(const float4*)&bs[k * 64 + tcol * 4];
      float ar[4] = {av.x, av.y, av.z, av.w};
      float br[4] = {bv.x, bv.y, bv.z, bv.w};
#pragma unroll
      for (int r = 0; r < 4; ++r)
#pragma unroll
        for (int j = 0; j < 4; ++j) acc[r][j] += ar[r] * br[j];
    }
  }
  int p = *picked;
#pragma unroll
  for (int r = 0; r < 4; ++r) {
    int row = r0 + trow * 4 + r;
    if (row >= N) continue;
    float o[4];
#pragma unroll
    for (int j = 0; j < 4; ++j) o[j] = acc[r][j];
    if (row == p) {
#pragma unroll
      for (int j = 0; j < 4; ++j) o[j] += bpick[tcol * 4 + j];
    }
    float4 xo = {o[0], o[1], o[2], o[3]};
    *(float4*)&x[(size_t)row * D + tcol * 4] = xo;
    float4 ho = {fmaxf(o[0], 0.f), fmaxf(o[1], 0.f), fmaxf(o[2], 0.f),
                 fmaxf(o[3], 0.f)};
    *(float4*)&h[(size_t)row * D + tcol * 4] = ho;
  }
}

// ---------------- SpMM scatter: pooled[src] += h[dst]  (one wave per edge)
__global__ __launch_bounds__(256) void k_scatter(
    const int* __restrict__ src, const int* __restrict__ dst,
    const float* __restrict__ h, float* __restrict__ pooled, int E) {
  int e = blockIdx.x * 4 + (threadIdx.x >> 6);
  if (e >= E) return;
  int d = threadIdx.x & 63;
  int s = src[e], t = dst[e];
  atomicAdd(&pooled[(size_t)s * D + d], h[(size_t)t * D + d]);
}

// ---------------- conv round: h = relu((inv_deg*pooled)@conv_w + conv_b + x)
__global__ __launch_bounds__(256) void k_conv(
    const float* __restrict__ pooled, const float* __restrict__ x,
    const float* __restrict__ cw, const float* __restrict__ cb,
    const float* __restrict__ invdeg, float* __restrict__ h, int N) {
  __shared__ float aT[64 * 68];
  __shared__ float bs[64 * 64];
  const int tid = threadIdx.x;
  const int r0 = blockIdx.x * 64;
  const int tcol = tid & 15, trow = tid >> 4;
  for (int i = tid; i < 64 * 64; i += 256) {
    int row = i >> 6, k = i & 63;
    int gr = r0 + row;
    float v = 0.0f;
    if (gr < N) v = pooled[(size_t)gr * D + k] * invdeg[gr];
    aT[k * 68 + row] = v;
  }
  for (int i = tid; i < 64 * 64; i += 256) bs[i] = cw[i];
  __syncthreads();
  float acc[4][4];
#pragma unroll
  for (int r = 0; r < 4; ++r)
#pragma unroll
    for (int j = 0; j < 4; ++j) acc[r][j] = cb[tcol * 4 + j];
#pragma unroll 8
  for (int k = 0; k < 64; ++k) {
    float4 av = *(const float4*)&aT[k * 68 + trow * 4];
    float4 bv = *(const float4*)&bs[k * 64 + tcol * 4];
    float ar[4] = {av.x, av.y, av.z, av.w};
    float br[4] = {bv.x, bv.y, bv.z, bv.w};
#pragma unroll
    for (int r = 0; r < 4; ++r)
#pragma unroll
      for (int j = 0; j < 4; ++j) acc[r][j] += ar[r] * br[j];
  }
#pragma unroll
  for (int r = 0; r < 4; ++r) {
    int row = r0 + trow * 4 + r;
    if (row >= N) continue;
    float4 xm = *(const float4*)&x[(size_t)row * D + tcol * 4];
    float4 o = {fmaxf(acc[r][0] + xm.x, 0.f), fmaxf(acc[r][1] + xm.y, 0.f),
                fmaxf(acc[r][2] + xm.z, 0.f), fmaxf(acc[r][3] + xm.w, 0.f)};
    *(float4*)&h[(size_t)row * D + tcol * 4] = o;
  }
}

// ---------------- graph sum (for mean) ----------------
__global__ __launch_bounds__(256) void k_gsum(const float* __restrict__ h,
                                              float* __restrict__ gsum, int N) {
  __shared__ float red[4][64];
  const int tid = threadIdx.x;
  const int col = tid & 63, rg = tid >> 6;
  float acc = 0.0f;
  for (int r = blockIdx.x * 4 + rg; r < N; r += gridDim.x * 4)
    acc += h[(size_t)r * D + col];
  red[rg][col] = acc;
  __syncthreads();
  if (tid < 64)
    atomicAdd(&gsum[tid], red[0][tid] + red[1][tid] + red[2][tid] + red[3][tid]);
}

// ---------------- small: te, gb_term, v, c ----------------
// small layout: [0:64] gsum, [64:128] gb_term, [128:192] v, [192] c
__global__ __launch_bounds__(64) void k_small(
    const float* __restrict__ h, const float* __restrict__ lin1_w,
    const float* __restrict__ lin1_b, const float* __restrict__ out_w,
    const float* __restrict__ out_b, const int* __restrict__ tgt,
    float* __restrict__ small, int N) {
  __shared__ float te[64];
  __shared__ float gbs[64];
  int j = threadIdx.x;
  int t = *tgt;
  te[j] = h[(size_t)t * D + j];
  gbs[j] = small[j] / (float)N;
  __syncthreads();
  float acc = lin1_b[j];
  for (int k = 0; k < 64; ++k) acc += gbs[k] * lin1_w[(64 + k) * 64 + j];
  small[64 + j] = acc;
  float vv = 0.0f;
  for (int d = 0; d < 64; ++d) vv += out_w[j * 64 + d] * te[d];
  small[128 + j] = vv;
  if (j == 0) {
    float c = 0.0f;
    for (int d = 0; d < 64; ++d) c += out_b[d] * te[d];
    small[192] = c;
  }
}

// ---------------- final: hid = relu(h@lin1A + gb_term), q = hid.v + c
__global__ __launch_bounds__(256) void k_final(
    const float* __restrict__ h, const float* __restrict__ lin1_w,
    const float* __restrict__ small, float* __restrict__ q, int N) {
  __shared__ float aT[64 * 68];
  __shared__ float bs[64 * 64];
  const int tid = threadIdx.x;
  const int r0 = blockIdx.x * 64;
  const int tcol = tid & 15, trow = tid >> 4;
  for (int i = tid; i < 64 * 64; i += 256) {
    int row = i >> 6, k = i & 63;
    int gr = r0 + row;
    aT[k * 68 + row] = (gr < N) ? h[(size_t)gr * D + k] : 0.0f;
  }
  for (int i = tid; i < 64 * 64; i += 256) bs[i] = lin1_w[i];  // rows 0..63
  __syncthreads();
  float acc[4][4];
#pragma unroll
  for (int r = 0; r < 4; ++r)
#pragma unroll
    for (int j = 0; j < 4; ++j) acc[r][j] = small[64 + tcol * 4 + j];
#pragma unroll 8
  for (int k = 0; k < 64; ++k) {
    float4 av = *(const float4*)&aT[k * 68 + trow * 4];
    float4 bv = *(const float4*)&bs[k * 64 + tcol * 4];
    float ar[4] = {av.x, av.y, av.z, av.w};
    float br[4] = {bv.x, bv.y, bv.z, bv.w};
#pragma unroll
    for (int r = 0; r < 4; ++r)
#pragma unroll
      for (int j = 0; j < 4; ++j) acc[r][j] += ar[r] * br[j];
  }
  float4 v = *(const float4*)&small[128 + tcol * 4];
  float c = small[192];
#pragma unroll
  for (int r = 0; r < 4; ++r) {
    float p = fmaxf(acc[r][0], 0.f) * v.x + fmaxf(acc[r][1], 0.f) * v.y +
              fmaxf(acc[r][2], 0.f) * v.z + fmaxf(acc[r][3], 0.f) * v.w;
    p += __shfl_xor(p, 1);
    p += __shfl_xor(p, 2);
    p += __shfl_xor(p, 4);
    p += __shfl_xor(p, 8);
    int row = r0 + trow * 4 + r;
    if (tcol == 0 && row < N) q[row] = p + c;
  }
}

extern "C" void kernel_launch(void* const* d_in, const int* in_sizes, int n_in,
                              void* d_out, int out_size, void* d_ws,
                              size_t ws_size, hipStream_t stream) {
  const float* nf = (const float*)d_in[0];
  const float* w_n2l = (const float*)d_in[1];
  const float* b_n2l = (const float*)d_in[2];
  const float* bpick = (const float*)d_in[3];
  const float* conv_w = (const float*)d_in[4];
  const float* conv_b = (const float*)d_in[5];
  const float* lin1_w = (const float*)d_in[6];
  const float* lin1_b = (const float*)d_in[7];
  const float* out_w = (const float*)d_in[8];
  const float* out_b = (const float*)d_in[9];
  const int* esrc = (const int*)d_in[10];
  const int* edst = (const int*)d_in[11];
  const int* tgt = (const int*)d_in[12];
  const int* picked = (const int*)d_in[13];
  float* q = (float*)d_out;

  const int N = in_sizes[0] / F;
  const int E = in_sizes[10];

  char* ws = (char*)d_ws;
  size_t nd = (size_t)N * D * sizeof(float);
  float* x = (float*)(ws);
  float* h = (float*)(ws + nd);
  float* pooled = (float*)(ws + 2 * nd);
  float* invdeg = (float*)(ws + 3 * nd);
  size_t invdeg_bytes = (((size_t)N * 4) + 255) / 256 * 256;
  float* small = (float*)(ws + 3 * nd + invdeg_bytes);

  hipMemsetAsync(invdeg, 0, (size_t)N * 4, stream);
  hipMemsetAsync(small, 0, 256 * 4, stream);
  k_deg<<<(E + 255) / 256, 256, 0, stream>>>(esrc, invdeg, E);
  k_invdeg<<<(N + 255) / 256, 256, 0, stream>>>(invdeg, N);

  int nb = (N + 63) / 64;
  k_input<<<nb, 256, 0, stream>>>(nf, w_n2l, b_n2l, bpick, picked, x, h, N);

  for (int lv = 0; lv < 2; ++lv) {
    hipMemsetAsync(pooled, 0, nd, stream);
    k_scatter<<<(E + 3) / 4, 256, 0, stream>>>(esrc, edst, h, pooled, E);
    k_conv<<<nb, 256, 0, stream>>>(pooled, x, conv_w, conv_b, invdeg, h, N);
  }

  k_gsum<<<512, 256, 0, stream>>>(h, small, N);
  k_small<<<1, 64, 0, stream>>>(h, lin1_w, lin1_b, out_w, out_b, tgt, small, N);
  k_final<<<nb, 256, 0, stream>>>(h, lin1_w, small, q, N);
}

// Round 2
// 1346.586 us; speedup vs baseline: 2.5158x; 2.5158x over previous
//
#include <hip/hip_runtime.h>

#define D 64
#define F 128

// ---------------- CSR build ----------------
__global__ __launch_bounds__(256) void k_hist(const int* __restrict__ src,
                                              int* __restrict__ cnt, int E) {
  int i = blockIdx.x * 256 + threadIdx.x;
  if (i < E) atomicAdd(&cnt[src[i]], 1);
}

// per-block exclusive scan of cnt -> rowptr, block totals -> bsum, invdeg
__global__ __launch_bounds__(256) void k_scan_block(
    const int* __restrict__ cnt, int* __restrict__ rowptr,
    int* __restrict__ bsum, float* __restrict__ invdeg, int N) {
  __shared__ int s[256];
  int i = blockIdx.x * 256 + threadIdx.x;
  int v = (i < N) ? cnt[i] : 0;
  if (i < N) invdeg[i] = 1.0f / fmaxf((float)v, 1.0f);
  s[threadIdx.x] = v;
  __syncthreads();
  for (int off = 1; off < 256; off <<= 1) {
    int t = (threadIdx.x >= off) ? s[threadIdx.x - off] : 0;
    __syncthreads();
    s[threadIdx.x] += t;
    __syncthreads();
  }
  if (i < N) rowptr[i] = s[threadIdx.x] - v;
  if (threadIdx.x == 255) bsum[blockIdx.x] = s[255];
}

// single-block exclusive scan of bsum (nb <= 1024)
__global__ __launch_bounds__(1024) void k_scan_bsum(int* __restrict__ bsum,
                                                    int nb) {
  __shared__ int s[1024];
  int v = (threadIdx.x < nb) ? bsum[threadIdx.x] : 0;
  s[threadIdx.x] = v;
  __syncthreads();
  for (int off = 1; off < 1024; off <<= 1) {
    int t = (threadIdx.x >= off) ? s[threadIdx.x - off] : 0;
    __syncthreads();
    s[threadIdx.x] += t;
    __syncthreads();
  }
  if (threadIdx.x < nb) bsum[threadIdx.x] = s[threadIdx.x] - v;
}

__global__ __launch_bounds__(256) void k_scan_add(int* __restrict__ rowptr,
                                                  const int* __restrict__ bsum,
                                                  int N, int E) {
  int i = blockIdx.x * 256 + threadIdx.x;
  if (i < N) rowptr[i] += bsum[i >> 8];
  if (i == 0) rowptr[N] = E;
}

__global__ __launch_bounds__(256) void k_bucket(
    const int* __restrict__ src, const int* __restrict__ dst,
    const int* __restrict__ rowptr, int* __restrict__ cursor,
    int* __restrict__ adj, int E) {
  int i = blockIdx.x * 256 + threadIdx.x;
  if (i < E) {
    int s = src[i];
    int pos = atomicAdd(&cursor[s], 1);
    adj[rowptr[s] + pos] = dst[i];
  }
}

// ---------------- SpMM gather: pooled[s] = invdeg[s] * sum h[adj[e]] ----------
__global__ __launch_bounds__(256) void k_gather(
    const int* __restrict__ rowptr, const int* __restrict__ adj,
    const float* __restrict__ h, const float* __restrict__ invdeg,
    float* __restrict__ pooled, int N) {
  int s = blockIdx.x * 4 + (threadIdx.x >> 6);
  if (s >= N) return;
  int d = threadIdx.x & 63;
  int e0 = rowptr[s], e1 = rowptr[s + 1];
  float acc = 0.0f;
  int e = e0;
  for (; e + 4 <= e1; e += 4) {
    int t0 = adj[e], t1 = adj[e + 1], t2 = adj[e + 2], t3 = adj[e + 3];
    float v0 = h[(size_t)t0 * D + d];
    float v1 = h[(size_t)t1 * D + d];
    float v2 = h[(size_t)t2 * D + d];
    float v3 = h[(size_t)t3 * D + d];
    acc += v0 + v1 + v2 + v3;
  }
  for (; e < e1; ++e) acc += h[(size_t)adj[e] * D + d];
  pooled[(size_t)s * D + d] = acc * invdeg[s];
}

// ---------------- input projection: x = nf@w + b (+picked bias), h = relu(x)
__global__ __launch_bounds__(256) void k_input(
    const float* __restrict__ nf, const float* __restrict__ w,
    const float* __restrict__ bias, const float* __restrict__ bpick,
    const int* __restrict__ picked, float* __restrict__ x,
    float* __restrict__ h, int N) {
  __shared__ float aT[64 * 68];
  __shared__ float bs[64 * 64];
  const int tid = threadIdx.x;
  const int r0 = blockIdx.x * 64;
  const int tcol = tid & 15, trow = tid >> 4;
  float acc[4][4];
#pragma unroll
  for (int r = 0; r < 4; ++r)
#pragma unroll
    for (int j = 0; j < 4; ++j) acc[r][j] = bias[tcol * 4 + j];

  for (int kc = 0; kc < F; kc += 64) {
    if (kc) __syncthreads();
    for (int i = tid; i < 64 * 64; i += 256) {
      int row = i >> 6, k = i & 63;
      int gr = r0 + row;
      aT[k * 68 + row] = (gr < N) ? nf[(size_t)gr * F + kc + k] : 0.0f;
    }
    for (int i = tid; i < 64 * 64; i += 256) bs[i] = w[kc * 64 + i];
    __syncthreads();
#pragma unroll 8
    for (int k = 0; k < 64; ++k) {
      float4 av = *(const float4*)&aT[k * 68 + trow * 4];
      float4 bv = *(const float4*)&bs[k * 64 + tcol * 4];
      float ar[4] = {av.x, av.y, av.z, av.w};
      float br[4] = {bv.x, bv.y, bv.z, bv.w};
#pragma unroll
      for (int r = 0; r < 4; ++r)
#pragma unroll
        for (int j = 0; j < 4; ++j) acc[r][j] += ar[r] * br[j];
    }
  }
  int p = *picked;
#pragma unroll
  for (int r = 0; r < 4; ++r) {
    int row = r0 + trow * 4 + r;
    if (row >= N) continue;
    float o[4];
#pragma unroll
    for (int j = 0; j < 4; ++j) o[j] = acc[r][j];
    if (row == p) {
#pragma unroll
      for (int j = 0; j < 4; ++j) o[j] += bpick[tcol * 4 + j];
    }
    float4 xo = {o[0], o[1], o[2], o[3]};
    *(float4*)&x[(size_t)row * D + tcol * 4] = xo;
    float4 ho = {fmaxf(o[0], 0.f), fmaxf(o[1], 0.f), fmaxf(o[2], 0.f),
                 fmaxf(o[3], 0.f)};
    *(float4*)&h[(size_t)row * D + tcol * 4] = ho;
  }
}

// ---------------- conv round: h = relu(pooled@conv_w + conv_b + x) ----------
__global__ __launch_bounds__(256) void k_conv(
    const float* __restrict__ pooled, const float* __restrict__ x,
    const float* __restrict__ cw, const float* __restrict__ cb,
    float* __restrict__ h, int N) {
  __shared__ float aT[64 * 68];
  __shared__ float bs[64 * 64];
  const int tid = threadIdx.x;
  const int r0 = blockIdx.x * 64;
  const int tcol = tid & 15, trow = tid >> 4;
  for (int i = tid; i < 64 * 64; i += 256) {
    int row = i >> 6, k = i & 63;
    int gr = r0 + row;
    aT[k * 68 + row] = (gr < N) ? pooled[(size_t)gr * D + k] : 0.0f;
  }
  for (int i = tid; i < 64 * 64; i += 256) bs[i] = cw[i];
  __syncthreads();
  float acc[4][4];
#pragma unroll
  for (int r = 0; r < 4; ++r)
#pragma unroll
    for (int j = 0; j < 4; ++j) acc[r][j] = cb[tcol * 4 + j];
#pragma unroll 8
  for (int k = 0; k < 64; ++k) {
    float4 av = *(const float4*)&aT[k * 68 + trow * 4];
    float4 bv = *(const float4*)&bs[k * 64 + tcol * 4];
    float ar[4] = {av.x, av.y, av.z, av.w};
    float br[4] = {bv.x, bv.y, bv.z, bv.w};
#pragma unroll
    for (int r = 0; r < 4; ++r)
#pragma unroll
      for (int j = 0; j < 4; ++j) acc[r][j] += ar[r] * br[j];
  }
#pragma unroll
  for (int r = 0; r < 4; ++r) {
    int row = r0 + trow * 4 + r;
    if (row >= N) continue;
    float4 xm = *(const float4*)&x[(size_t)row * D + tcol * 4];
    float4 o = {fmaxf(acc[r][0] + xm.x, 0.f), fmaxf(acc[r][1] + xm.y, 0.f),
                fmaxf(acc[r][2] + xm.z, 0.f), fmaxf(acc[r][3] + xm.w, 0.f)};
    *(float4*)&h[(size_t)row * D + tcol * 4] = o;
  }
}

// ---------------- graph sum (for mean) ----------------
__global__ __launch_bounds__(256) void k_gsum(const float* __restrict__ h,
                                              float* __restrict__ gsum, int N) {
  __shared__ float red[4][64];
  const int tid = threadIdx.x;
  const int col = tid & 63, rg = tid >> 6;
  float acc = 0.0f;
  for (int r = blockIdx.x * 4 + rg; r < N; r += gridDim.x * 4)
    acc += h[(size_t)r * D + col];
  red[rg][col] = acc;
  __syncthreads();
  if (tid < 64)
    atomicAdd(&gsum[tid], red[0][tid] + red[1][tid] + red[2][tid] + red[3][tid]);
}

// ---------------- small: te, gb_term, v, c ----------------
// small layout: [0:64] gsum, [64:128] gb_term, [128:192] v, [192] c
__global__ __launch_bounds__(64) void k_small(
    const float* __restrict__ h, const float* __restrict__ lin1_w,
    const float* __restrict__ lin1_b, const float* __restrict__ out_w,
    const float* __restrict__ out_b, const int* __restrict__ tgt,
    float* __restrict__ small, int N) {
  __shared__ float te[64];
  __shared__ float gbs[64];
  int j = threadIdx.x;
  int t = *tgt;
  te[j] = h[(size_t)t * D + j];
  gbs[j] = small[j] / (float)N;
  __syncthreads();
  float acc = lin1_b[j];
  for (int k = 0; k < 64; ++k) acc += gbs[k] * lin1_w[(64 + k) * 64 + j];
  small[64 + j] = acc;
  float vv = 0.0f;
  for (int d = 0; d < 64; ++d) vv += out_w[j * 64 + d] * te[d];
  small[128 + j] = vv;
  if (j == 0) {
    float c = 0.0f;
    for (int d = 0; d < 64; ++d) c += out_b[d] * te[d];
    small[192] = c;
  }
}

// ---------------- final: hid = relu(h@lin1A + gb_term), q = hid.v + c
__global__ __launch_bounds__(256) void k_final(
    const float* __restrict__ h, const float* __restrict__ lin1_w,
    const float* __restrict__ small, float* __restrict__ q, int N) {
  __shared__ float aT[64 * 68];
  __shared__ float bs[64 * 64];
  const int tid = threadIdx.x;
  const int r0 = blockIdx.x * 64;
  const int tcol = tid & 15, trow = tid >> 4;
  for (int i = tid; i < 64 * 64; i += 256) {
    int row = i >> 6, k = i & 63;
    int gr = r0 + row;
    aT[k * 68 + row] = (gr < N) ? h[(size_t)gr * D + k] : 0.0f;
  }
  for (int i = tid; i < 64 * 64; i += 256) bs[i] = lin1_w[i];
  __syncthreads();
  float acc[4][4];
#pragma unroll
  for (int r = 0; r < 4; ++r)
#pragma unroll
    for (int j = 0; j < 4; ++j) acc[r][j] = small[64 + tcol * 4 + j];
#pragma unroll 8
  for (int k = 0; k < 64; ++k) {
    float4 av = *(const float4*)&aT[k * 68 + trow * 4];
    float4 bv = *(const float4*)&bs[k * 64 + tcol * 4];
    float ar[4] = {av.x, av.y, av.z, av.w};
    float br[4] = {bv.x, bv.y, bv.z, bv.w};
#pragma unroll
    for (int r = 0; r < 4; ++r)
#pragma unroll
      for (int j = 0; j < 4; ++j) acc[r][j] += ar[r] * br[j];
  }
  float4 v = *(const float4*)&small[128 + tcol * 4];
  float c = small[192];
#pragma unroll
  for (int r = 0; r < 4; ++r) {
    float p = fmaxf(acc[r][0], 0.f) * v.x + fmaxf(acc[r][1], 0.f) * v.y +
              fmaxf(acc[r][2], 0.f) * v.z + fmaxf(acc[r][3], 0.f) * v.w;
    p += __shfl_xor(p, 1);
    p += __shfl_xor(p, 2);
    p += __shfl_xor(p, 4);
    p += __shfl_xor(p, 8);
    int row = r0 + trow * 4 + r;
    if (tcol == 0 && row < N) q[row] = p + c;
  }
}

extern "C" void kernel_launch(void* const* d_in, const int* in_sizes, int n_in,
                              void* d_out, int out_size, void* d_ws,
                              size_t ws_size, hipStream_t stream) {
  const float* nf = (const float*)d_in[0];
  const float* w_n2l = (const float*)d_in[1];
  const float* b_n2l = (const float*)d_in[2];
  const float* bpick = (const float*)d_in[3];
  const float* conv_w = (const float*)d_in[4];
  const float* conv_b = (const float*)d_in[5];
  const float* lin1_w = (const float*)d_in[6];
  const float* lin1_b = (const float*)d_in[7];
  const float* out_w = (const float*)d_in[8];
  const float* out_b = (const float*)d_in[9];
  const int* esrc = (const int*)d_in[10];
  const int* edst = (const int*)d_in[11];
  const int* tgt = (const int*)d_in[12];
  const int* picked = (const int*)d_in[13];
  float* q = (float*)d_out;

  const int N = in_sizes[0] / F;
  const int E = in_sizes[10];

  char* ws = (char*)d_ws;
  size_t off = 0;
  auto alloc = [&](size_t bytes) {
    void* p = ws + off;
    off = (off + bytes + 255) & ~(size_t)255;
    return p;
  };
  size_t nd = (size_t)N * D * sizeof(float);
  float* x = (float*)alloc(nd);
  float* h = (float*)alloc(nd);
  float* pooled = (float*)alloc(nd);  // first N ints reused as bucket cursor
  float* invdeg = (float*)alloc((size_t)N * 4);
  int* rowptr = (int*)alloc((size_t)(N + 1) * 4);
  int* cnt = (int*)alloc((size_t)N * 4);
  int* adj = (int*)alloc((size_t)E * 4);
  int* bsum = (int*)alloc(4096);
  float* small = (float*)alloc(1024);
  int* cursor = (int*)pooled;

  const int nb1 = (N + 255) / 256;  // 782 <= 1024

  hipMemsetAsync(cnt, 0, (size_t)N * 4, stream);
  hipMemsetAsync(cursor, 0, (size_t)N * 4, stream);
  hipMemsetAsync(small, 0, 256 * 4, stream);

  // CSR build
  k_hist<<<(E + 255) / 256, 256, 0, stream>>>(esrc, cnt, E);
  k_scan_block<<<nb1, 256, 0, stream>>>(cnt, rowptr, bsum, invdeg, N);
  k_scan_bsum<<<1, 1024, 0, stream>>>(bsum, nb1);
  k_scan_add<<<nb1, 256, 0, stream>>>(rowptr, bsum, N, E);
  k_bucket<<<(E + 255) / 256, 256, 0, stream>>>(esrc, edst, rowptr, cursor,
                                                adj, E);

  int nb = (N + 63) / 64;
  k_input<<<nb, 256, 0, stream>>>(nf, w_n2l, b_n2l, bpick, picked, x, h, N);

  for (int lv = 0; lv < 2; ++lv) {
    k_gather<<<(N + 3) / 4, 256, 0, stream>>>(rowptr, adj, h, invdeg, pooled,
                                              N);
    k_conv<<<nb, 256, 0, stream>>>(pooled, x, conv_w, conv_b, h, N);
  }

  k_gsum<<<512, 256, 0, stream>>>(h, small, N);
  k_small<<<1, 64, 0, stream>>>(h, lin1_w, lin1_b, out_w, out_b, tgt, small, N);
  k_final<<<nb, 256, 0, stream>>>(h, lin1_w, small, q, N);
}

// Round 3
// 935.790 us; speedup vs baseline: 3.6202x; 1.4390x over previous
//
#include <hip/hip_runtime.h>

#define D 64
#define F 128
#define LDSCAP 12288  // staged adj ints per 256-row bucket (48KB)

__device__ __forceinline__ unsigned short f2bf(float f) {
  unsigned int u = __float_as_uint(f);
  unsigned int r = (u + 0x7FFFu + ((u >> 16) & 1u)) >> 16;
  return (unsigned short)r;
}
__device__ __forceinline__ float bf2f(unsigned short h) {
  return __uint_as_float(((unsigned int)h) << 16);
}

// ---------------- coarse histogram: cbh[s>>8]++ ----------------
__global__ __launch_bounds__(256) void k_chist(const int* __restrict__ src,
                                               int* __restrict__ cbh, int E) {
  __shared__ int lh[1024];
  for (int i = threadIdx.x; i < 1024; i += 256) lh[i] = 0;
  __syncthreads();
  for (int i = blockIdx.x * 256 + threadIdx.x; i < E; i += gridDim.x * 256)
    atomicAdd(&lh[src[i] >> 8], 1);
  __syncthreads();
  for (int i = threadIdx.x; i < 1024; i += 256)
    if (lh[i]) atomicAdd(&cbh[i], lh[i]);
}

// ---------------- coarse scan: cbase (exclusive), gcur init --------------
__global__ __launch_bounds__(1024) void k_cscan(const int* __restrict__ cbh,
                                                int* __restrict__ cbase,
                                                int* __restrict__ gcur,
                                                int* __restrict__ rowptr,
                                                int nbuck, int N, int E) {
  __shared__ int s[1024];
  int tid = threadIdx.x;
  int v = (tid < nbuck) ? cbh[tid] : 0;
  s[tid] = v;
  __syncthreads();
  for (int off = 1; off < 1024; off <<= 1) {
    int t = (tid >= off) ? s[tid - off] : 0;
    __syncthreads();
    s[tid] += t;
    __syncthreads();
  }
  if (tid < nbuck) {
    int ex = s[tid] - v;
    cbase[tid] = ex;
    gcur[tid] = ex;
  }
  if (tid == 0) {
    cbase[nbuck] = E;
    rowptr[N] = E;
  }
}

// ---------------- partition pass 1: packed words grouped by coarse bucket
// word = (src&255)<<24 | dst   (dst < 2^24)
#define CH 24576
__global__ __launch_bounds__(256) void k_part1(const int* __restrict__ src,
                                               const int* __restrict__ dst,
                                               int* __restrict__ gcur,
                                               unsigned int* __restrict__ words,
                                               int E) {
  __shared__ int lcnt[1024];
  __shared__ int lbase[1024];
  const int tid = threadIdx.x;
  const int e0 = blockIdx.x * CH;
  const int e1 = min(E, e0 + CH);
  for (int i = tid; i < 1024; i += 256) lcnt[i] = 0;
  __syncthreads();
  for (int i = e0 + tid; i < e1; i += 256) atomicAdd(&lcnt[src[i] >> 8], 1);
  __syncthreads();
  for (int b = tid; b < 1024; b += 256) {
    int c = lcnt[b];
    lbase[b] = c ? atomicAdd(&gcur[b], c) : 0;
    lcnt[b] = 0;  // becomes run counter
  }
  __syncthreads();
  for (int i = e0 + tid; i < e1; i += 256) {
    int s = src[i];
    int b = s >> 8;
    int pos = atomicAdd(&lcnt[b], 1);
    words[lbase[b] + pos] = ((unsigned int)(s & 255) << 24) | (unsigned int)dst[i];
  }
}

// ---------------- partition pass 2: per-bucket rowptr/invdeg/adj ----------
__global__ __launch_bounds__(256) void k_part2(
    const unsigned int* __restrict__ words, const int* __restrict__ cbase,
    int* __restrict__ rowptr, float* __restrict__ invdeg,
    int* __restrict__ adj, int N) {
  __shared__ int lcnt[256];
  __shared__ int lscan[256];
  __shared__ int lrun[256];
  __shared__ int ladj[LDSCAP];
  const int tid = threadIdx.x;
  const int b = blockIdx.x;
  const int p0 = cbase[b], p1 = cbase[b + 1];
  const int cnt = p1 - p0;
  lcnt[tid] = 0;
  __syncthreads();
  for (int i = tid; i < cnt; i += 256)
    atomicAdd(&lcnt[words[p0 + i] >> 24], 1);
  __syncthreads();
  int v = lcnt[tid];
  lscan[tid] = v;
  __syncthreads();
  for (int off = 1; off < 256; off <<= 1) {
    int t = (tid >= off) ? lscan[tid - off] : 0;
    __syncthreads();
    lscan[tid] += t;
    __syncthreads();
  }
  int ex = lscan[tid] - v;
  int row = b * 256 + tid;
  if (row < N) {
    rowptr[row] = p0 + ex;
    invdeg[row] = 1.0f / fmaxf((float)v, 1.0f);
  }
  lcnt[tid] = ex;  // exclusive offsets
  lrun[tid] = 0;
  __syncthreads();
  if (cnt <= LDSCAP) {
    for (int i = tid; i < cnt; i += 256) {
      unsigned int w = words[p0 + i];
      int r = w >> 24;
      int pos = atomicAdd(&lrun[r], 1);
      ladj[lcnt[r] + pos] = (int)(w & 0xFFFFFFu);
    }
    __syncthreads();
    for (int i = tid; i < cnt; i += 256) adj[p0 + i] = ladj[i];
  } else {  // pathological bucket: direct (rare)
    for (int i = tid; i < cnt; i += 256) {
      unsigned int w = words[p0 + i];
      int r = w >> 24;
      int pos = atomicAdd(&lrun[r], 1);
      adj[p0 + lcnt[r] + pos] = (int)(w & 0xFFFFFFu);
    }
  }
}

// ---------------- SpMM gather (bf16 h): 2 edges per wave ------------------
__global__ __launch_bounds__(256) void k_gather(
    const int* __restrict__ rowptr, const int* __restrict__ adj,
    const unsigned short* __restrict__ hb, const float* __restrict__ invdeg,
    float* __restrict__ pooled, int N) {
  int s = blockIdx.x * 4 + (threadIdx.x >> 6);
  if (s >= N) return;
  const int lane = threadIdx.x & 63;
  const int half = lane >> 5;
  const int l = lane & 31;
  const int e0 = rowptr[s], e1 = rowptr[s + 1];
  float acc0 = 0.0f, acc1 = 0.0f;
  int e = e0 + half;
  for (; e + 2 < e1; e += 4) {
    int t0 = adj[e], t1 = adj[e + 2];
    unsigned int w0 = *(const unsigned int*)&hb[(size_t)t0 * D + 2 * l];
    unsigned int w1 = *(const unsigned int*)&hb[(size_t)t1 * D + 2 * l];
    acc0 += bf2f((unsigned short)(w0 & 0xFFFF)) +
            bf2f((unsigned short)(w1 & 0xFFFF));
    acc1 += bf2f((unsigned short)(w0 >> 16)) + bf2f((unsigned short)(w1 >> 16));
  }
  if (e < e1) {
    int t0 = adj[e];
    unsigned int w0 = *(const unsigned int*)&hb[(size_t)t0 * D + 2 * l];
    acc0 += bf2f((unsigned short)(w0 & 0xFFFF));
    acc1 += bf2f((unsigned short)(w0 >> 16));
  }
  acc0 += __shfl_xor(acc0, 32);
  acc1 += __shfl_xor(acc1, 32);
  if (half == 0) {
    float iv = invdeg[s];
    float2 o = {acc0 * iv, acc1 * iv};
    *(float2*)&pooled[(size_t)s * D + 2 * l] = o;
  }
}

// ---------------- input projection ----------------
__global__ __launch_bounds__(256) void k_input(
    const float* __restrict__ nf, const float* __restrict__ w,
    const float* __restrict__ bias, const float* __restrict__ bpick,
    const int* __restrict__ picked, float* __restrict__ x,
    float* __restrict__ h, unsigned short* __restrict__ hb, int N) {
  __shared__ float aT[64 * 68];
  __shared__ float bs[64 * 64];
  const int tid = threadIdx.x;
  const int r0 = blockIdx.x * 64;
  const int tcol = tid & 15, trow = tid >> 4;
  float acc[4][4];
#pragma unroll
  for (int r = 0; r < 4; ++r)
#pragma unroll
    for (int j = 0; j < 4; ++j) acc[r][j] = bias[tcol * 4 + j];

  for (int kc = 0; kc < F; kc += 64) {
    if (kc) __syncthreads();
    for (int i = tid; i < 64 * 64; i += 256) {
      int row = i >> 6, k = i & 63;
      int gr = r0 + row;
      aT[k * 68 + row] = (gr < N) ? nf[(size_t)gr * F + kc + k] : 0.0f;
    }
    for (int i = tid; i < 64 * 64; i += 256) bs[i] = w[kc * 64 + i];
    __syncthreads();
#pragma unroll 8
    for (int k = 0; k < 64; ++k) {
      float4 av = *(const float4*)&aT[k * 68 + trow * 4];
      float4 bv = *(const float4*)&bs[k * 64 + tcol * 4];
      float ar[4] = {av.x, av.y, av.z, av.w};
      float br[4] = {bv.x, bv.y, bv.z, bv.w};
#pragma unroll
      for (int r = 0; r < 4; ++r)
#pragma unroll
        for (int j = 0; j < 4; ++j) acc[r][j] += ar[r] * br[j];
    }
  }
  int p = *picked;
#pragma unroll
  for (int r = 0; r < 4; ++r) {
    int row = r0 + trow * 4 + r;
    if (row >= N) continue;
    float o[4];
#pragma unroll
    for (int j = 0; j < 4; ++j) o[j] = acc[r][j];
    if (row == p) {
#pragma unroll
      for (int j = 0; j < 4; ++j) o[j] += bpick[tcol * 4 + j];
    }
    *(float4*)&x[(size_t)row * D + tcol * 4] = make_float4(o[0], o[1], o[2], o[3]);
    float h0 = fmaxf(o[0], 0.f), h1 = fmaxf(o[1], 0.f);
    float h2 = fmaxf(o[2], 0.f), h3 = fmaxf(o[3], 0.f);
    *(float4*)&h[(size_t)row * D + tcol * 4] = make_float4(h0, h1, h2, h3);
    ushort4 hv = {f2bf(h0), f2bf(h1), f2bf(h2), f2bf(h3)};
    *(ushort4*)&hb[(size_t)row * D + tcol * 4] = hv;
  }
}

// ---------------- conv round ----------------
__global__ __launch_bounds__(256) void k_conv(
    const float* __restrict__ pooled, const float* __restrict__ x,
    const float* __restrict__ cw, const float* __restrict__ cb,
    float* __restrict__ h, unsigned short* __restrict__ hb, int write_hb,
    int N) {
  __shared__ float aT[64 * 68];
  __shared__ float bs[64 * 64];
  const int tid = threadIdx.x;
  const int r0 = blockIdx.x * 64;
  const int tcol = tid & 15, trow = tid >> 4;
  for (int i = tid; i < 64 * 64; i += 256) {
    int row = i >> 6, k = i & 63;
    int gr = r0 + row;
    aT[k * 68 + row] = (gr < N) ? pooled[(size_t)gr * D + k] : 0.0f;
  }
  for (int i = tid; i < 64 * 64; i += 256) bs[i] = cw[i];
  __syncthreads();
  float acc[4][4];
#pragma unroll
  for (int r = 0; r < 4; ++r)
#pragma unroll
    for (int j = 0; j < 4; ++j) acc[r][j] = cb[tcol * 4 + j];
#pragma unroll 8
  for (int k = 0; k < 64; ++k) {
    float4 av = *(const float4*)&aT[k * 68 + trow * 4];
    float4 bv = *(const float4*)&bs[k * 64 + tcol * 4];
    float ar[4] = {av.x, av.y, av.z, av.w};
    float br[4] = {bv.x, bv.y, bv.z, bv.w};
#pragma unroll
    for (int r = 0; r < 4; ++r)
#pragma unroll
      for (int j = 0; j < 4; ++j) acc[r][j] += ar[r] * br[j];
  }
#pragma unroll
  for (int r = 0; r < 4; ++r) {
    int row = r0 + trow * 4 + r;
    if (row >= N) continue;
    float4 xm = *(const float4*)&x[(size_t)row * D + tcol * 4];
    float h0 = fmaxf(acc[r][0] + xm.x, 0.f), h1 = fmaxf(acc[r][1] + xm.y, 0.f);
    float h2 = fmaxf(acc[r][2] + xm.z, 0.f), h3 = fmaxf(acc[r][3] + xm.w, 0.f);
    *(float4*)&h[(size_t)row * D + tcol * 4] = make_float4(h0, h1, h2, h3);
    if (write_hb) {
      ushort4 hv = {f2bf(h0), f2bf(h1), f2bf(h2), f2bf(h3)};
      *(ushort4*)&hb[(size_t)row * D + tcol * 4] = hv;
    }
  }
}

// ---------------- graph sum ----------------
__global__ __launch_bounds__(256) void k_gsum(const float* __restrict__ h,
                                              float* __restrict__ gsum, int N) {
  __shared__ float red[4][64];
  const int tid = threadIdx.x;
  const int col = tid & 63, rg = tid >> 6;
  float acc = 0.0f;
  for (int r = blockIdx.x * 4 + rg; r < N; r += gridDim.x * 4)
    acc += h[(size_t)r * D + col];
  red[rg][col] = acc;
  __syncthreads();
  if (tid < 64)
    atomicAdd(&gsum[tid], red[0][tid] + red[1][tid] + red[2][tid] + red[3][tid]);
}

// ---------------- small: te, gb_term, v, c ----------------
__global__ __launch_bounds__(64) void k_small(
    const float* __restrict__ h, const float* __restrict__ lin1_w,
    const float* __restrict__ lin1_b, const float* __restrict__ out_w,
    const float* __restrict__ out_b, const int* __restrict__ tgt,
    float* __restrict__ small, int N) {
  __shared__ float te[64];
  __shared__ float gbs[64];
  int j = threadIdx.x;
  int t = *tgt;
  te[j] = h[(size_t)t * D + j];
  gbs[j] = small[j] / (float)N;
  __syncthreads();
  float acc = lin1_b[j];
  for (int k = 0; k < 64; ++k) acc += gbs[k] * lin1_w[(64 + k) * 64 + j];
  small[64 + j] = acc;
  float vv = 0.0f;
  for (int d = 0; d < 64; ++d) vv += out_w[j * 64 + d] * te[d];
  small[128 + j] = vv;
  if (j == 0) {
    float c = 0.0f;
    for (int d = 0; d < 64; ++d) c += out_b[d] * te[d];
    small[192] = c;
  }
}

// ---------------- final ----------------
__global__ __launch_bounds__(256) void k_final(
    const float* __restrict__ h, const float* __restrict__ lin1_w,
    const float* __restrict__ small, float* __restrict__ q, int N) {
  __shared__ float aT[64 * 68];
  __shared__ float bs[64 * 64];
  const int tid = threadIdx.x;
  const int r0 = blockIdx.x * 64;
  const int tcol = tid & 15, trow = tid >> 4;
  for (int i = tid; i < 64 * 64; i += 256) {
    int row = i >> 6, k = i & 63;
    int gr = r0 + row;
    aT[k * 68 + row] = (gr < N) ? h[(size_t)gr * D + k] : 0.0f;
  }
  for (int i = tid; i < 64 * 64; i += 256) bs[i] = lin1_w[i];
  __syncthreads();
  float acc[4][4];
#pragma unroll
  for (int r = 0; r < 4; ++r)
#pragma unroll
    for (int j = 0; j < 4; ++j) acc[r][j] = small[64 + tcol * 4 + j];
#pragma unroll 8
  for (int k = 0; k < 64; ++k) {
    float4 av = *(const float4*)&aT[k * 68 + trow * 4];
    float4 bv = *(const float4*)&bs[k * 64 + tcol * 4];
    float ar[4] = {av.x, av.y, av.z, av.w};
    float br[4] = {bv.x, bv.y, bv.z, bv.w};
#pragma unroll
    for (int r = 0; r < 4; ++r)
#pragma unroll
      for (int j = 0; j < 4; ++j) acc[r][j] += ar[r] * br[j];
  }
  float4 v = *(const float4*)&small[128 + tcol * 4];
  float c = small[192];
#pragma unroll
  for (int r = 0; r < 4; ++r) {
    float p = fmaxf(acc[r][0], 0.f) * v.x + fmaxf(acc[r][1], 0.f) * v.y +
              fmaxf(acc[r][2], 0.f) * v.z + fmaxf(acc[r][3], 0.f) * v.w;
    p += __shfl_xor(p, 1);
    p += __shfl_xor(p, 2);
    p += __shfl_xor(p, 4);
    p += __shfl_xor(p, 8);
    int row = r0 + trow * 4 + r;
    if (tcol == 0 && row < N) q[row] = p + c;
  }
}

extern "C" void kernel_launch(void* const* d_in, const int* in_sizes, int n_in,
                              void* d_out, int out_size, void* d_ws,
                              size_t ws_size, hipStream_t stream) {
  const float* nf = (const float*)d_in[0];
  const float* w_n2l = (const float*)d_in[1];
  const float* b_n2l = (const float*)d_in[2];
  const float* bpick = (const float*)d_in[3];
  const float* conv_w = (const float*)d_in[4];
  const float* conv_b = (const float*)d_in[5];
  const float* lin1_w = (const float*)d_in[6];
  const float* lin1_b = (const float*)d_in[7];
  const float* out_w = (const float*)d_in[8];
  const float* out_b = (const float*)d_in[9];
  const int* esrc = (const int*)d_in[10];
  const int* edst = (const int*)d_in[11];
  const int* tgt = (const int*)d_in[12];
  const int* picked = (const int*)d_in[13];
  float* q = (float*)d_out;

  const int N = in_sizes[0] / F;
  const int E = in_sizes[10];
  const int NBUCK = (N + 255) / 256;  // 782 (<=1024)

  char* ws = (char*)d_ws;
  size_t off = 0;
  auto alloc = [&](size_t bytes) {
    void* p = ws + off;
    off = (off + bytes + 255) & ~(size_t)255;
    return p;
  };
  size_t nd = (size_t)N * D * sizeof(float);
  float* x = (float*)alloc(nd);
  float* h = (float*)alloc(nd);
  unsigned short* hb = (unsigned short*)alloc((size_t)N * D * 2);
  float* pooled = (float*)alloc(nd);
  float* invdeg = (float*)alloc((size_t)N * 4);
  int* rowptr = (int*)alloc((size_t)(N + 1) * 4);
  int* adj = (int*)alloc((size_t)E * 4);
  int* cbh = (int*)alloc(4096 + 8);
  int* cbase = (int*)alloc(4096 + 8);
  int* gcur = (int*)alloc(4096 + 8);
  float* small = (float*)alloc(1024);
  unsigned int* words = (unsigned int*)x;  // alias: x written after k_part2

  hipMemsetAsync(cbh, 0, 4096, stream);
  hipMemsetAsync(small, 0, 256 * 4, stream);

  // CSR build: coarse hist -> scan -> partition -> per-bucket finalize
  k_chist<<<512, 256, 0, stream>>>(esrc, cbh, E);
  k_cscan<<<1, 1024, 0, stream>>>(cbh, cbase, gcur, rowptr, NBUCK, N, E);
  k_part1<<<(E + CH - 1) / CH, 256, 0, stream>>>(esrc, edst, gcur, words, E);
  k_part2<<<NBUCK, 256, 0, stream>>>(words, cbase, rowptr, invdeg, adj, N);

  int nb = (N + 63) / 64;
  k_input<<<nb, 256, 0, stream>>>(nf, w_n2l, b_n2l, bpick, picked, x, h, hb, N);

  for (int lv = 0; lv < 2; ++lv) {
    k_gather<<<(N + 3) / 4, 256, 0, stream>>>(rowptr, adj, hb, invdeg, pooled, N);
    k_conv<<<nb, 256, 0, stream>>>(pooled, x, conv_w, conv_b, h, hb,
                                   (lv == 0) ? 1 : 0, N);
  }

  k_gsum<<<512, 256, 0, stream>>>(h, small, N);
  k_small<<<1, 64, 0, stream>>>(h, lin1_w, lin1_b, out_w, out_b, tgt, small, N);
  k_final<<<nb, 256, 0, stream>>>(h, lin1_w, small, q, N);
}

// Round 5
// 782.288 us; speedup vs baseline: 4.3306x; 1.1962x over previous
//
#include <hip/hip_runtime.h>

#define D 64
#define F 128
#define LDSCAP 12288  // staged adj ints per 256-row bucket (48KB)

__device__ __forceinline__ unsigned short f2bf(float f) {
  unsigned int u = __float_as_uint(f);
  unsigned int r = (u + 0x7FFFu + ((u >> 16) & 1u)) >> 16;
  return (unsigned short)r;
}
__device__ __forceinline__ float bf2f(unsigned short h) {
  return __uint_as_float(((unsigned int)h) << 16);
}

// ---------------- coarse histogram: cbh[s>>8]++ ----------------
__global__ __launch_bounds__(256) void k_chist(const int* __restrict__ src,
                                               int* __restrict__ cbh, int E) {
  __shared__ int lh[1024];
  for (int i = threadIdx.x; i < 1024; i += 256) lh[i] = 0;
  __syncthreads();
  for (int i = blockIdx.x * 256 + threadIdx.x; i < E; i += gridDim.x * 256)
    atomicAdd(&lh[src[i] >> 8], 1);
  __syncthreads();
  for (int i = threadIdx.x; i < 1024; i += 256)
    if (lh[i]) atomicAdd(&cbh[i], lh[i]);
}

// ---------------- coarse scan ----------------
__global__ __launch_bounds__(1024) void k_cscan(const int* __restrict__ cbh,
                                                int* __restrict__ cbase,
                                                int* __restrict__ gcur,
                                                int* __restrict__ rowptr,
                                                int nbuck, int N, int E) {
  __shared__ int s[1024];
  int tid = threadIdx.x;
  int v = (tid < nbuck) ? cbh[tid] : 0;
  s[tid] = v;
  __syncthreads();
  for (int off = 1; off < 1024; off <<= 1) {
    int t = (tid >= off) ? s[tid - off] : 0;
    __syncthreads();
    s[tid] += t;
    __syncthreads();
  }
  if (tid < nbuck) {
    int ex = s[tid] - v;
    cbase[tid] = ex;
    gcur[tid] = ex;
  }
  if (tid == 0) {
    cbase[nbuck] = E;
    rowptr[N] = E;
  }
}

// ---------------- partition pass 1 ----------------
#define CH 24576
__global__ __launch_bounds__(256) void k_part1(const int* __restrict__ src,
                                               const int* __restrict__ dst,
                                               int* __restrict__ gcur,
                                               unsigned int* __restrict__ words,
                                               int E) {
  __shared__ int lcnt[1024];
  __shared__ int lbase[1024];
  const int tid = threadIdx.x;
  const int e0 = blockIdx.x * CH;
  const int e1 = min(E, e0 + CH);
  for (int i = tid; i < 1024; i += 256) lcnt[i] = 0;
  __syncthreads();
  for (int i = e0 + tid; i < e1; i += 256) atomicAdd(&lcnt[src[i] >> 8], 1);
  __syncthreads();
  for (int b = tid; b < 1024; b += 256) {
    int c = lcnt[b];
    lbase[b] = c ? atomicAdd(&gcur[b], c) : 0;
    lcnt[b] = 0;
  }
  __syncthreads();
  for (int i = e0 + tid; i < e1; i += 256) {
    int s = src[i];
    int b = s >> 8;
    int pos = atomicAdd(&lcnt[b], 1);
    words[lbase[b] + pos] = ((unsigned int)(s & 255) << 24) | (unsigned int)dst[i];
  }
}

// ---------------- partition pass 2 ----------------
__global__ __launch_bounds__(256) void k_part2(
    const unsigned int* __restrict__ words, const int* __restrict__ cbase,
    int* __restrict__ rowptr, float* __restrict__ invdeg,
    int* __restrict__ adj, int N) {
  __shared__ int lcnt[256];
  __shared__ int lscan[256];
  __shared__ int lrun[256];
  __shared__ int ladj[LDSCAP];
  const int tid = threadIdx.x;
  const int b = blockIdx.x;
  const int p0 = cbase[b], p1 = cbase[b + 1];
  const int cnt = p1 - p0;
  lcnt[tid] = 0;
  __syncthreads();
  for (int i = tid; i < cnt; i += 256)
    atomicAdd(&lcnt[words[p0 + i] >> 24], 1);
  __syncthreads();
  int v = lcnt[tid];
  lscan[tid] = v;
  __syncthreads();
  for (int off = 1; off < 256; off <<= 1) {
    int t = (tid >= off) ? lscan[tid - off] : 0;
    __syncthreads();
    lscan[tid] += t;
    __syncthreads();
  }
  int ex = lscan[tid] - v;
  int row = b * 256 + tid;
  if (row < N) {
    rowptr[row] = p0 + ex;
    invdeg[row] = 1.0f / fmaxf((float)v, 1.0f);
  }
  lcnt[tid] = ex;
  lrun[tid] = 0;
  __syncthreads();
  if (cnt <= LDSCAP) {
    for (int i = tid; i < cnt; i += 256) {
      unsigned int w = words[p0 + i];
      int r = w >> 24;
      int pos = atomicAdd(&lrun[r], 1);
      ladj[lcnt[r] + pos] = (int)(w & 0xFFFFFFu);
    }
    __syncthreads();
    for (int i = tid; i < cnt; i += 256) adj[p0 + i] = ladj[i];
  } else {
    for (int i = tid; i < cnt; i += 256) {
      unsigned int w = words[p0 + i];
      int r = w >> 24;
      int pos = atomicAdd(&lrun[r], 1);
      adj[p0 + lcnt[r] + pos] = (int)(w & 0xFFFFFFu);
    }
  }
}

// ---------------- SpMM gather: 8 lanes/edge, 8 edge-slots, unroll 2 -------
// 16 x 16B loads in flight per wave.
#define ACCUM(V_)                                          \
  acc0 += bf2f((unsigned short)((V_).x & 0xFFFF));         \
  acc1 += bf2f((unsigned short)((V_).x >> 16));            \
  acc2 += bf2f((unsigned short)((V_).y & 0xFFFF));         \
  acc3 += bf2f((unsigned short)((V_).y >> 16));            \
  acc4 += bf2f((unsigned short)((V_).z & 0xFFFF));         \
  acc5 += bf2f((unsigned short)((V_).z >> 16));            \
  acc6 += bf2f((unsigned short)((V_).w & 0xFFFF));         \
  acc7 += bf2f((unsigned short)((V_).w >> 16));
#define RED(a)            \
  a += __shfl_xor(a, 8);  \
  a += __shfl_xor(a, 16); \
  a += __shfl_xor(a, 32);

__global__ __launch_bounds__(256) void k_gather(
    const int* __restrict__ rowptr, const int* __restrict__ adj,
    const unsigned short* __restrict__ hb, const float* __restrict__ invdeg,
    float* __restrict__ pooled, int N) {
  int s = blockIdx.x * 4 + (threadIdx.x >> 6);
  if (s >= N) return;
  const int lane = threadIdx.x & 63;
  const int slot = lane >> 3;  // edge slot 0..7
  const int dp = lane & 7;     // dims 8*dp .. 8*dp+7
  const int e0 = rowptr[s], e1 = rowptr[s + 1];
  float acc0 = 0, acc1 = 0, acc2 = 0, acc3 = 0;
  float acc4 = 0, acc5 = 0, acc6 = 0, acc7 = 0;
  int e = e0 + slot;
  for (; e + 8 < e1; e += 16) {
    int t0 = adj[e], t1 = adj[e + 8];
    uint4 w0 = *(const uint4*)&hb[(size_t)t0 * D + dp * 8];
    uint4 w1 = *(const uint4*)&hb[(size_t)t1 * D + dp * 8];
    ACCUM(w0)
    ACCUM(w1)
  }
  if (e < e1) {
    int t0 = adj[e];
    uint4 w0 = *(const uint4*)&hb[(size_t)t0 * D + dp * 8];
    ACCUM(w0)
  }
  RED(acc0) RED(acc1) RED(acc2) RED(acc3)
  RED(acc4) RED(acc5) RED(acc6) RED(acc7)
  if (slot == 0) {
    float iv = invdeg[s];
    float4 o0 = {acc0 * iv, acc1 * iv, acc2 * iv, acc3 * iv};
    float4 o1 = {acc4 * iv, acc5 * iv, acc6 * iv, acc7 * iv};
    *(float4*)&pooled[(size_t)s * D + dp * 8] = o0;
    *(float4*)&pooled[(size_t)s * D + dp * 8 + 4] = o1;
  }
}

// ---------------- input projection: x fp32 + hb bf16 (no fp32 h) ----------
__global__ __launch_bounds__(256) void k_input(
    const float* __restrict__ nf, const float* __restrict__ w,
    const float* __restrict__ bias, const float* __restrict__ bpick,
    const int* __restrict__ picked, float* __restrict__ x,
    unsigned short* __restrict__ hb, int N) {
  __shared__ float aT[64 * 68];
  __shared__ float bs[64 * 64];
  const int tid = threadIdx.x;
  const int r0 = blockIdx.x * 64;
  const int tcol = tid & 15, trow = tid >> 4;
  float acc[4][4];
#pragma unroll
  for (int r = 0; r < 4; ++r)
#pragma unroll
    for (int j = 0; j < 4; ++j) acc[r][j] = bias[tcol * 4 + j];

  for (int kc = 0; kc < F; kc += 64) {
    if (kc) __syncthreads();
    for (int i = tid; i < 64 * 64; i += 256) {
      int row = i >> 6, k = i & 63;
      int gr = r0 + row;
      aT[k * 68 + row] = (gr < N) ? nf[(size_t)gr * F + kc + k] : 0.0f;
    }
    for (int i = tid; i < 64 * 64; i += 256) bs[i] = w[kc * 64 + i];
    __syncthreads();
#pragma unroll 8
    for (int k = 0; k < 64; ++k) {
      float4 av = *(const float4*)&aT[k * 68 + trow * 4];
      float4 bv = *(const float4*)&bs[k * 64 + tcol * 4];
      float ar[4] = {av.x, av.y, av.z, av.w};
      float br[4] = {bv.x, bv.y, bv.z, bv.w};
#pragma unroll
      for (int r = 0; r < 4; ++r)
#pragma unroll
        for (int j = 0; j < 4; ++j) acc[r][j] += ar[r] * br[j];
    }
  }
  int p = *picked;
#pragma unroll
  for (int r = 0; r < 4; ++r) {
    int row = r0 + trow * 4 + r;
    if (row >= N) continue;
    float o[4];
#pragma unroll
    for (int j = 0; j < 4; ++j) o[j] = acc[r][j];
    if (row == p) {
#pragma unroll
      for (int j = 0; j < 4; ++j) o[j] += bpick[tcol * 4 + j];
    }
    *(float4*)&x[(size_t)row * D + tcol * 4] = make_float4(o[0], o[1], o[2], o[3]);
    ushort4 hv = {f2bf(fmaxf(o[0], 0.f)), f2bf(fmaxf(o[1], 0.f)),
                  f2bf(fmaxf(o[2], 0.f)), f2bf(fmaxf(o[3], 0.f))};
    *(ushort4*)&hb[(size_t)row * D + tcol * 4] = hv;
  }
}

// ---------------- conv round ----------------
// mode 0: write hb only (intermediate round)
// mode 1: write fp32 h + accumulate graph sum into gsum (final round)
__global__ __launch_bounds__(256) void k_conv(
    const float* __restrict__ pooled, const float* __restrict__ x,
    const float* __restrict__ cw, const float* __restrict__ cb,
    float* __restrict__ h, unsigned short* __restrict__ hb,
    float* __restrict__ gsum, int mode, int N) {
  __shared__ float aT[64 * 68];
  __shared__ float bs[64 * 64];
  __shared__ float gs[64];
  const int tid = threadIdx.x;
  const int r0 = blockIdx.x * 64;
  const int tcol = tid & 15, trow = tid >> 4;
  for (int i = tid; i < 64 * 64; i += 256) {
    int row = i >> 6, k = i & 63;
    int gr = r0 + row;
    aT[k * 68 + row] = (gr < N) ? pooled[(size_t)gr * D + k] : 0.0f;
  }
  for (int i = tid; i < 64 * 64; i += 256) bs[i] = cw[i];
  __syncthreads();
  float acc[4][4];
#pragma unroll
  for (int r = 0; r < 4; ++r)
#pragma unroll
    for (int j = 0; j < 4; ++j) acc[r][j] = cb[tcol * 4 + j];
#pragma unroll 8
  for (int k = 0; k < 64; ++k) {
    float4 av = *(const float4*)&aT[k * 68 + trow * 4];
    float4 bv = *(const float4*)&bs[k * 64 + tcol * 4];
    float ar[4] = {av.x, av.y, av.z, av.w};
    float br[4] = {bv.x, bv.y, bv.z, bv.w};
#pragma unroll
    for (int r = 0; r < 4; ++r)
#pragma unroll
      for (int j = 0; j < 4; ++j) acc[r][j] += ar[r] * br[j];
  }
  float colsum[4] = {0.f, 0.f, 0.f, 0.f};
#pragma unroll
  for (int r = 0; r < 4; ++r) {
    int row = r0 + trow * 4 + r;
    if (row >= N) continue;
    float4 xm = *(const float4*)&x[(size_t)row * D + tcol * 4];
    float h0 = fmaxf(acc[r][0] + xm.x, 0.f), h1 = fmaxf(acc[r][1] + xm.y, 0.f);
    float h2 = fmaxf(acc[r][2] + xm.z, 0.f), h3 = fmaxf(acc[r][3] + xm.w, 0.f);
    if (mode == 0) {
      ushort4 hv = {f2bf(h0), f2bf(h1), f2bf(h2), f2bf(h3)};
      *(ushort4*)&hb[(size_t)row * D + tcol * 4] = hv;
    } else {
      *(float4*)&h[(size_t)row * D + tcol * 4] = make_float4(h0, h1, h2, h3);
      colsum[0] += h0;
      colsum[1] += h1;
      colsum[2] += h2;
      colsum[3] += h3;
    }
  }
  if (mode == 1) {
    __syncthreads();
    if (tid < 64) gs[tid] = 0.0f;
    __syncthreads();
#pragma unroll
    for (int j = 0; j < 4; ++j) atomicAdd(&gs[tcol * 4 + j], colsum[j]);
    __syncthreads();
    if (tid < 64) atomicAdd(&gsum[tid], gs[tid]);
  }
}

// ---------------- small: te, gb_term, v, c ----------------
__global__ __launch_bounds__(64) void k_small(
    const float* __restrict__ h, const float* __restrict__ lin1_w,
    const float* __restrict__ lin1_b, const float* __restrict__ out_w,
    const float* __restrict__ out_b, const int* __restrict__ tgt,
    float* __restrict__ small, int N) {
  __shared__ float te[64];
  __shared__ float gbs[64];
  int j = threadIdx.x;
  int t = *tgt;
  te[j] = h[(size_t)t * D + j];
  gbs[j] = small[j] / (float)N;
  __syncthreads();
  float acc = lin1_b[j];
  for (int k = 0; k < 64; ++k) acc += gbs[k] * lin1_w[(64 + k) * 64 + j];
  small[64 + j] = acc;
  float vv = 0.0f;
  for (int d = 0; d < 64; ++d) vv += out_w[j * 64 + d] * te[d];
  small[128 + j] = vv;
  if (j == 0) {
    float c = 0.0f;
    for (int d = 0; d < 64; ++d) c += out_b[d] * te[d];
    small[192] = c;
  }
}

// ---------------- final ----------------
__global__ __launch_bounds__(256) void k_final(
    const float* __restrict__ h, const float* __restrict__ lin1_w,
    const float* __restrict__ small, float* __restrict__ q, int N) {
  __shared__ float aT[64 * 68];
  __shared__ float bs[64 * 64];
  const int tid = threadIdx.x;
  const int r0 = blockIdx.x * 64;
  const int tcol = tid & 15, trow = tid >> 4;
  for (int i = tid; i < 64 * 64; i += 256) {
    int row = i >> 6, k = i & 63;
    int gr = r0 + row;
    aT[k * 68 + row] = (gr < N) ? h[(size_t)gr * D + k] : 0.0f;
  }
  for (int i = tid; i < 64 * 64; i += 256) bs[i] = lin1_w[i];
  __syncthreads();
  float acc[4][4];
#pragma unroll
  for (int r = 0; r < 4; ++r)
#pragma unroll
    for (int j = 0; j < 4; ++j) acc[r][j] = small[64 + tcol * 4 + j];
#pragma unroll 8
  for (int k = 0; k < 64; ++k) {
    float4 av = *(const float4*)&aT[k * 68 + trow * 4];
    float4 bv = *(const float4*)&bs[k * 64 + tcol * 4];
    float ar[4] = {av.x, av.y, av.z, av.w};
    float br[4] = {bv.x, bv.y, bv.z, bv.w};
#pragma unroll
    for (int r = 0; r < 4; ++r)
#pragma unroll
      for (int j = 0; j < 4; ++j) acc[r][j] += ar[r] * br[j];
  }
  float4 v = *(const float4*)&small[128 + tcol * 4];
  float c = small[192];
#pragma unroll
  for (int r = 0; r < 4; ++r) {
    float p = fmaxf(acc[r][0], 0.f) * v.x + fmaxf(acc[r][1], 0.f) * v.y +
              fmaxf(acc[r][2], 0.f) * v.z + fmaxf(acc[r][3], 0.f) * v.w;
    p += __shfl_xor(p, 1);
    p += __shfl_xor(p, 2);
    p += __shfl_xor(p, 4);
    p += __shfl_xor(p, 8);
    int row = r0 + trow * 4 + r;
    if (tcol == 0 && row < N) q[row] = p + c;
  }
}

extern "C" void kernel_launch(void* const* d_in, const int* in_sizes, int n_in,
                              void* d_out, int out_size, void* d_ws,
                              size_t ws_size, hipStream_t stream) {
  const float* nf = (const float*)d_in[0];
  const float* w_n2l = (const float*)d_in[1];
  const float* b_n2l = (const float*)d_in[2];
  const float* bpick = (const float*)d_in[3];
  const float* conv_w = (const float*)d_in[4];
  const float* conv_b = (const float*)d_in[5];
  const float* lin1_w = (const float*)d_in[6];
  const float* lin1_b = (const float*)d_in[7];
  const float* out_w = (const float*)d_in[8];
  const float* out_b = (const float*)d_in[9];
  const int* esrc = (const int*)d_in[10];
  const int* edst = (const int*)d_in[11];
  const int* tgt = (const int*)d_in[12];
  const int* picked = (const int*)d_in[13];
  float* q = (float*)d_out;

  const int N = in_sizes[0] / F;
  const int E = in_sizes[10];
  const int NBUCK = (N + 255) / 256;

  char* ws = (char*)d_ws;
  size_t off = 0;
  auto alloc = [&](size_t bytes) {
    void* p = ws + off;
    off = (off + bytes + 255) & ~(size_t)255;
    return p;
  };
  size_t nd = (size_t)N * D * sizeof(float);
  float* x = (float*)alloc(nd);
  float* h = (float*)alloc(nd);
  unsigned short* hb = (unsigned short*)alloc((size_t)N * D * 2);
  float* pooled = (float*)alloc(nd);
  float* invdeg = (float*)alloc((size_t)N * 4);
  int* rowptr = (int*)alloc((size_t)(N + 1) * 4);
  int* adj = (int*)alloc((size_t)E * 4);
  int* cbh = (int*)alloc(4096 + 8);
  int* cbase = (int*)alloc(4096 + 8);
  int* gcur = (int*)alloc(4096 + 8);
  float* small = (float*)alloc(1024);
  unsigned int* words = (unsigned int*)x;  // alias: x written after k_part2

  (void)hipMemsetAsync(cbh, 0, 4096, stream);
  (void)hipMemsetAsync(small, 0, 256 * 4, stream);

  // CSR build
  k_chist<<<512, 256, 0, stream>>>(esrc, cbh, E);
  k_cscan<<<1, 1024, 0, stream>>>(cbh, cbase, gcur, rowptr, NBUCK, N, E);
  k_part1<<<(E + CH - 1) / CH, 256, 0, stream>>>(esrc, edst, gcur, words, E);
  k_part2<<<NBUCK, 256, 0, stream>>>(words, cbase, rowptr, invdeg, adj, N);

  int nb = (N + 63) / 64;
  k_input<<<nb, 256, 0, stream>>>(nf, w_n2l, b_n2l, bpick, picked, x, hb, N);

  for (int lv = 0; lv < 2; ++lv) {
    k_gather<<<(N + 3) / 4, 256, 0, stream>>>(rowptr, adj, hb, invdeg, pooled, N);
    k_conv<<<nb, 256, 0, stream>>>(pooled, x, conv_w, conv_b, h, hb, small,
                                   (lv == 0) ? 0 : 1, N);
  }

  k_small<<<1, 64, 0, stream>>>(h, lin1_w, lin1_b, out_w, out_b, tgt, small, N);
  k_final<<<nb, 256, 0, stream>>>(h, lin1_w, small, q, N);
}